// Round 4
// baseline (1639.977 us; speedup 1.0000x reference)
//
#include <hip/hip_runtime.h>

// IF-neuron, exact fp64 strategy. Round 3 passed (absmax 0.0) at 1249 us with
// MfmaUtil=37%, Occupancy=12% (1 wave/SIMD -> load latency unhidden).
// This round: K-split each 16x16 tile across 4 waves (grid 1024 blocks =
// 4 blocks/CU = 4 waves/SIMD), LDS-reduce partial x per t-step. fp64 summation
// order is decision-irrelevant (proven rounds 2 vs 3).

#define T_STEPS 32
#define B_DIM   128
#define K_DIM   2048
#define O_DIM   2048
#define KQ      (K_DIM / 4)    // 512 per wave

typedef double d4 __attribute__((ext_vector_type(4)));

// ---- prepass: W[o][k] -> wf[ot][k][i] = W[ot*16+i][k] ----
__global__ __launch_bounds__(256) void prep_w(const float* __restrict__ Wm,
                                              float* __restrict__ wf) {
    __shared__ float lds[16][65];
    const int kc = blockIdx.x, ot = blockIdx.y;
    const int k0 = kc * 64, o0 = ot * 16;
    const int c = threadIdx.x & 63;
    const int r4 = threadIdx.x >> 6;
#pragma unroll
    for (int rr = 0; rr < 4; ++rr) {
        int r = r4 * 4 + rr;
        lds[r][c] = Wm[(size_t)(o0 + r) * K_DIM + k0 + c];
    }
    __syncthreads();
    float* dst = wf + (size_t)ot * (K_DIM * 16) + (size_t)k0 * 16;
#pragma unroll
    for (int q = 0; q < 4; ++q) {
        int f = q * 256 + threadIdx.x;
        dst[f] = lds[f & 15][f >> 4];
    }
}

// ---- prepass: inp[t][b][k] -> af[t][bt][k][i] = inp[t][bt*16+i][k] ----
__global__ __launch_bounds__(256) void prep_a(const float* __restrict__ inp,
                                              float* __restrict__ af) {
    __shared__ float lds[16][65];
    const int kc = blockIdx.x, bt = blockIdx.y, t = blockIdx.z;
    const int k0 = kc * 64;
    const float* src = inp + (size_t)t * (B_DIM * K_DIM) + (size_t)(bt * 16) * K_DIM + k0;
    const int c = threadIdx.x & 63;
    const int r4 = threadIdx.x >> 6;
#pragma unroll
    for (int rr = 0; rr < 4; ++rr) {
        int r = r4 * 4 + rr;
        lds[r][c] = src[(size_t)r * K_DIM + c];
    }
    __syncthreads();
    float* dst = af + (size_t)t * (B_DIM * K_DIM) + (size_t)bt * (K_DIM * 16) + (size_t)k0 * 16;
#pragma unroll
    for (int q = 0; q < 4; ++q) {
        int f = q * 256 + threadIdx.x;
        dst[f] = lds[f & 15][f >> 4];
    }
}

// ---- fused f64-MFMA GEMM + IF scan, K-split over 4 waves ----
// grid (128 o-tiles, 8 b-tiles), 256 threads = 4 waves; wave w owns K range
// [w*512, w*512+512) of the block's single 16x16 (b,o) tile.
template <bool PRE>
__global__ __launch_bounds__(256, 4) void if_main(
    const float* __restrict__ af, const float* __restrict__ wf,
    const float* __restrict__ inp, const float* __restrict__ Wm,
    const float* __restrict__ bias, const float* __restrict__ mem0,
    float* __restrict__ outp)
{
    const int tid = threadIdx.x;
    const int l   = tid & 63;
    const int wv  = tid >> 6;          // k-quarter index
    const int o0  = blockIdx.x * 16;
    const int b0  = blockIdx.y * 16;
    const int col = l & 15;
    const int g   = l >> 4;

    __shared__ double lds_x[4][4][64];  // [j][wv][lane] — 2-way bank access, free

    // ---- runtime D-layout probe (2 MFMAs), as verified in round 3 ----
    const double p_val = (g == 0) ? (double)col : 0.0;
    const double p_one = (g == 0) ? 1.0 : 0.0;
    d4 z = {0.0, 0.0, 0.0, 0.0};
    d4 dr = __builtin_amdgcn_mfma_f64_16x16x4f64(p_val, p_one, z, 0, 0, 0); // row idx
    d4 dc = __builtin_amdgcn_mfma_f64_16x16x4f64(p_one, p_val, z, 0, 0, 0); // col idx

    int rix[4], cix[4];
    bool okl = true;
#pragma unroll
    for (int j = 0; j < 4; ++j) {
        double r = dr[j], c = dc[j];
        bool rin = (r >= 0.0) && (r < 16.0);
        bool cin = (c >= 0.0) && (c < 16.0);
        int ri = rin ? (int)r : 0;
        int ci = cin ? (int)c : 0;
        okl = okl && rin && cin && ((double)ri == r) && ((double)ci == c);
        rix[j] = ri; cix[j] = ci;
    }
#pragma unroll
    for (int a = 0; a < 4; ++a)
#pragma unroll
        for (int b2 = a + 1; b2 < 4; ++b2)
            okl = okl && !(rix[a] == rix[b2] && cix[a] == cix[b2]);
    const bool ok = (__all(okl ? 1 : 0) != 0);
    if (!ok) {
#pragma unroll
        for (int j = 0; j < 4; ++j) { rix[j] = g * 4 + j; cix[j] = col; }
    }

    double mem[4], biasd[4];
    int cnt[4]; bool sp[4];
#pragma unroll
    for (int j = 0; j < 4; ++j) {
        const int o = o0 + cix[j];
        biasd[j] = (double)bias[o];
        mem[j]   = (double)mem0[(size_t)(b0 + rix[j]) * O_DIM + o];
        sp[j] = false; cnt[j] = 0;
    }

    const float* pa = nullptr;
    const float* pw = nullptr;
    if (PRE) {
        pa = af + (size_t)blockIdx.y * (K_DIM * 16) + (size_t)(wv * KQ) * 16 + l;
        pw = wf + (size_t)blockIdx.x * (K_DIM * 16) + (size_t)(wv * KQ) * 16 + l;
    }

    for (int t = 0; t < T_STEPS; ++t) {
        d4 xs;
        if (ok) {
            d4 acc0 = {0.0, 0.0, 0.0, 0.0};
            d4 acc1 = {0.0, 0.0, 0.0, 0.0};
            const float* pat = PRE ? (pa + (size_t)t * (B_DIM * K_DIM)) : nullptr;
            const float* pit = PRE ? nullptr : (inp + (size_t)t * (B_DIM * K_DIM));
#pragma unroll 4
            for (int kk = 0; kk < KQ; kk += 8) {
                double a0, w0, a1, w1;
                if (PRE) {
                    a0 = (double)pat[kk * 16];
                    w0 = (double)pw[kk * 16];
                    a1 = (double)pat[kk * 16 + 64];
                    w1 = (double)pw[kk * 16 + 64];
                } else {
                    const int kb = wv * KQ + kk;
                    a0 = (double)pit[(size_t)(b0 + col) * K_DIM + kb + g];
                    w0 = (double)Wm[(size_t)(o0 + col) * K_DIM + kb + g];
                    a1 = (double)pit[(size_t)(b0 + col) * K_DIM + kb + 4 + g];
                    w1 = (double)Wm[(size_t)(o0 + col) * K_DIM + kb + 4 + g];
                }
                acc0 = __builtin_amdgcn_mfma_f64_16x16x4f64(a0, w0, acc0, 0, 0, 0);
                acc1 = __builtin_amdgcn_mfma_f64_16x16x4f64(a1, w1, acc1, 0, 0, 0);
            }
#pragma unroll
            for (int j = 0; j < 4; ++j) xs[j] = acc0[j] + acc1[j];
        } else {
            // scalar-f64 safety net over this wave's K quarter
#pragma unroll
            for (int j = 0; j < 4; ++j) {
                const float* ar = inp + ((size_t)t * B_DIM + b0 + rix[j]) * K_DIM + wv * KQ;
                const float* wr = Wm + (size_t)(o0 + cix[j]) * K_DIM + wv * KQ;
                double s0 = 0.0, s1 = 0.0;
                for (int k = 0; k < KQ; k += 2) {
                    s0 = fma((double)ar[k],     (double)wr[k],     s0);
                    s1 = fma((double)ar[k + 1], (double)wr[k + 1], s1);
                }
                xs[j] = s0 + s1;
            }
        }

        // ---- reduce partial x across the 4 k-quarter waves ----
#pragma unroll
        for (int j = 0; j < 4; ++j) lds_x[j][wv][l] = xs[j];
        __syncthreads();
        d4 xsum;
#pragma unroll
        for (int j = 0; j < 4; ++j)
            xsum[j] = (lds_x[j][0][l] + lds_x[j][1][l]) +
                      (lds_x[j][2][l] + lds_x[j][3][l]);
        __syncthreads();

#pragma unroll
        for (int j = 0; j < 4; ++j) {
            double m_ = (sp[j] ? 0.0 : mem[j]) + (xsum[j] + biasd[j]);
            sp[j]  = (m_ > 1.0);
            mem[j] = m_;
            cnt[j] += sp[j] ? 1 : 0;
        }
    }

    if (wv == 0) {
#pragma unroll
        for (int j = 0; j < 4; ++j)
            outp[(size_t)(b0 + rix[j]) * O_DIM + o0 + cix[j]] = (float)cnt[j] * 0.03125f;
    }
}

extern "C" void kernel_launch(void* const* d_in, const int* in_sizes, int n_in,
                              void* d_out, int out_size, void* d_ws, size_t ws_size,
                              hipStream_t stream) {
    const float* inp  = (const float*)d_in[0];   // [32,128,2048]
    const float* Wm   = (const float*)d_in[1];   // [2048,2048]
    const float* bias = (const float*)d_in[2];   // [2048]
    const float* mem0 = (const float*)d_in[3];   // [128,2048]
    float* outp = (float*)d_out;                 // [128,2048]

    const size_t wf_elems = (size_t)O_DIM * K_DIM;           // 16 MB
    const size_t af_elems = (size_t)T_STEPS * B_DIM * K_DIM; // 32 MB
    const size_t need = (wf_elems + af_elems) * sizeof(float);

    if (ws_size >= need) {
        float* wf = (float*)d_ws;
        float* af = wf + wf_elems;
        prep_w<<<dim3(32, 128), 256, 0, stream>>>(Wm, wf);
        prep_a<<<dim3(32, 8, 32), 256, 0, stream>>>(inp, af);
        if_main<true><<<dim3(128, 8), 256, 0, stream>>>(af, wf, inp, Wm, bias, mem0, outp);
    } else {
        if_main<false><<<dim3(128, 8), 256, 0, stream>>>(nullptr, nullptr, inp, Wm, bias, mem0, outp);
    }
}

// Round 5
// 531.719 us; speedup vs baseline: 3.0843x; 3.0843x over previous
//
#include <hip/hip_runtime.h>

// IF-neuron, exact fp64 strategy, two-phase (proven round 2: any fp64 order matches).
// Phase 1: blocked f64-MFMA GEMM x = inp @ W^T  (M=4096=T*B, N=2048, K=2048),
//          128x128 block tile, 8 waves x (32x64), K-chunk 32 double-buffered in LDS (f32).
// Phase 2: IF scan over t (memory-bound, ~30us), round-2-verified.
// Runtime D-layout probe for v_mfma_f64_16x16x4f64 (proven rounds 3-4); scalar fallback.

#define T_ALL 32
#define B_DIM 128
#define O_DIM 2048
#define K_DIM 2048
#define BO    (B_DIM * O_DIM)

#define BK    32
#define NCH   (K_DIM / BK)     // 64 k-chunks
#define LDST  36               // f32 row stride in LDS (16B-aligned, conflict-free reads)

typedef double d4 __attribute__((ext_vector_type(4)));

// ---- Phase 1: f64 MFMA GEMM: xbuf[m][n] = sum_k inp[m0g+m][k] * W[n][k] ----
// grid (16 n-tiles, tc m-tiles), 512 threads = 8 waves (4 m-bands x 2 o-bands)
__global__ __launch_bounds__(512, 4) void gemm_f64_mfma(
    const float* __restrict__ inp, const float* __restrict__ Wm,
    double* __restrict__ xbuf, int m0g)   // m0g = global row offset of this chunk
{
    __shared__ float lds[2][2][128 * LDST];   // [buf][A=0/B=1] : 73728 B
    __shared__ int ok_flag;

    const int tid = threadIdx.x;
    const int l   = tid & 63;
    const int wv  = tid >> 6;            // 0..7
    const int col = l & 15;
    const int g   = l >> 4;
    const int r_base = (wv & 3) * 32;    // m sub-band within 128
    const int c_base = (wv >> 2) * 64;   // n sub-band within 128
    const int n0  = blockIdx.x * 128;
    const int mloc = blockIdx.y * 128;   // row offset within this chunk's xbuf

    // ---- runtime D-layout probe (verified on this HW, rounds 3-4) ----
    const double p_val = (g == 0) ? (double)col : 0.0;
    const double p_one = (g == 0) ? 1.0 : 0.0;
    d4 z = {0.0, 0.0, 0.0, 0.0};
    d4 drr = __builtin_amdgcn_mfma_f64_16x16x4f64(p_val, p_one, z, 0, 0, 0);
    d4 dcc = __builtin_amdgcn_mfma_f64_16x16x4f64(p_one, p_val, z, 0, 0, 0);
    int rix[4], cix[4];
    bool okl = true;
#pragma unroll
    for (int j = 0; j < 4; ++j) {
        double r = drr[j], c = dcc[j];
        bool rin = (r >= 0.0) && (r < 16.0);
        bool cin = (c >= 0.0) && (c < 16.0);
        int ri = rin ? (int)r : 0;
        int ci = cin ? (int)c : 0;
        okl = okl && rin && cin && ((double)ri == r) && ((double)ci == c);
        rix[j] = ri; cix[j] = ci;
    }
#pragma unroll
    for (int a = 0; a < 4; ++a)
#pragma unroll
        for (int b2 = a + 1; b2 < 4; ++b2)
            okl = okl && !(rix[a] == rix[b2] && cix[a] == cix[b2]);
    if (tid == 0) ok_flag = 0;
    __syncthreads();
    if (!__all(okl ? 1 : 0)) { if (l == 0) atomicOr(&ok_flag, 1); }
    __syncthreads();
    const bool ok = (ok_flag == 0);

    const float* Arow = inp + (size_t)(m0g + mloc) * K_DIM;
    const float* Brow = Wm + (size_t)n0 * K_DIM;

    if (ok) {
        d4 acc[2][4];
#pragma unroll
        for (int i = 0; i < 2; ++i)
#pragma unroll
            for (int n = 0; n < 4; ++n) acc[i][n] = z;

        const int row0 = tid & 127,        q0 = tid >> 7;        // load slot 0
        const int row1 = (tid + 512) & 127, q1 = (tid + 512) >> 7; // load slot 1
        float4 pA0, pA1, pB0, pB1;

        // prologue: chunk 0
        pA0 = *(const float4*)(Arow + (size_t)row0 * K_DIM + 4 * q0);
        pA1 = *(const float4*)(Arow + (size_t)row1 * K_DIM + 4 * q1);
        pB0 = *(const float4*)(Brow + (size_t)row0 * K_DIM + 4 * q0);
        pB1 = *(const float4*)(Brow + (size_t)row1 * K_DIM + 4 * q1);
        *(float4*)&lds[0][0][row0 * LDST + 4 * q0] = pA0;
        *(float4*)&lds[0][0][row1 * LDST + 4 * q1] = pA1;
        *(float4*)&lds[0][1][row0 * LDST + 4 * q0] = pB0;
        *(float4*)&lds[0][1][row1 * LDST + 4 * q1] = pB1;
        __syncthreads();

        for (int c = 0; c < NCH; ++c) {
            const int cur = c & 1;
            if (c + 1 < NCH) {
                const int k0 = (c + 1) * BK;
                pA0 = *(const float4*)(Arow + (size_t)row0 * K_DIM + k0 + 4 * q0);
                pA1 = *(const float4*)(Arow + (size_t)row1 * K_DIM + k0 + 4 * q1);
                pB0 = *(const float4*)(Brow + (size_t)row0 * K_DIM + k0 + 4 * q0);
                pB1 = *(const float4*)(Brow + (size_t)row1 * K_DIM + k0 + 4 * q1);
            }
            const float* Al = &lds[cur][0][0];
            const float* Bl = &lds[cur][1][0];
#pragma unroll
            for (int ks = 0; ks < 8; ++ks) {
                const int kl = 4 * ks + g;
                double a0 = (double)Al[(r_base + col) * LDST + kl];
                double a1 = (double)Al[(r_base + 16 + col) * LDST + kl];
                double b0 = (double)Bl[(c_base + col) * LDST + kl];
                double b1 = (double)Bl[(c_base + 16 + col) * LDST + kl];
                double b2 = (double)Bl[(c_base + 32 + col) * LDST + kl];
                double b3 = (double)Bl[(c_base + 48 + col) * LDST + kl];
                acc[0][0] = __builtin_amdgcn_mfma_f64_16x16x4f64(a0, b0, acc[0][0], 0, 0, 0);
                acc[0][1] = __builtin_amdgcn_mfma_f64_16x16x4f64(a0, b1, acc[0][1], 0, 0, 0);
                acc[0][2] = __builtin_amdgcn_mfma_f64_16x16x4f64(a0, b2, acc[0][2], 0, 0, 0);
                acc[0][3] = __builtin_amdgcn_mfma_f64_16x16x4f64(a0, b3, acc[0][3], 0, 0, 0);
                acc[1][0] = __builtin_amdgcn_mfma_f64_16x16x4f64(a1, b0, acc[1][0], 0, 0, 0);
                acc[1][1] = __builtin_amdgcn_mfma_f64_16x16x4f64(a1, b1, acc[1][1], 0, 0, 0);
                acc[1][2] = __builtin_amdgcn_mfma_f64_16x16x4f64(a1, b2, acc[1][2], 0, 0, 0);
                acc[1][3] = __builtin_amdgcn_mfma_f64_16x16x4f64(a1, b3, acc[1][3], 0, 0, 0);
            }
            if (c + 1 < NCH) {
                const int nb = cur ^ 1;
                *(float4*)&lds[nb][0][row0 * LDST + 4 * q0] = pA0;
                *(float4*)&lds[nb][0][row1 * LDST + 4 * q1] = pA1;
                *(float4*)&lds[nb][1][row0 * LDST + 4 * q0] = pB0;
                *(float4*)&lds[nb][1][row1 * LDST + 4 * q1] = pB1;
            }
            __syncthreads();
        }

        double* xr = xbuf + (size_t)mloc * O_DIM + n0;
#pragma unroll
        for (int i = 0; i < 2; ++i)
#pragma unroll
            for (int n = 0; n < 4; ++n)
#pragma unroll
                for (int j = 0; j < 4; ++j)
                    xr[(size_t)(r_base + 16 * i + rix[j]) * O_DIM + c_base + 16 * n + cix[j]] = acc[i][n][j];
    } else {
        // scalar safety net (never taken on verified HW, but exact)
        for (int e = tid; e < 128 * 128; e += 512) {
            const int r = e >> 7, cc = e & 127;
            const float* ar = Arow + (size_t)r * K_DIM;
            const float* wr = Brow + (size_t)cc * K_DIM;
            double s0 = 0.0, s1 = 0.0;
            for (int k = 0; k < K_DIM; k += 2) {
                s0 = fma((double)ar[k],     (double)wr[k],     s0);
                s1 = fma((double)ar[k + 1], (double)wr[k + 1], s1);
            }
            xbuf[(size_t)(mloc + r) * O_DIM + n0 + cc] = s0 + s1;
        }
    }
}

// ---- Phase 2: IF scan (round-2-verified) ----
__global__ __launch_bounds__(256) void if_scan(
    const double* __restrict__ xbuf, const float* __restrict__ bias,
    const float* __restrict__ mem0,
    double* __restrict__ mem_st, int* __restrict__ cnt_st,
    float* __restrict__ outp, int t_begin, int t_count)
{
    const int i = blockIdx.x * 256 + threadIdx.x;
    const int o = i & (O_DIM - 1);

    double mem; int cnt; bool sp;
    if (t_begin == 0) { mem = (double)mem0[i]; cnt = 0; sp = false; }
    else { mem = mem_st[i]; int c = cnt_st[i]; cnt = c & 0xffff; sp = (c >> 16) & 1; }

    const double biasd = (double)bias[o];
    for (int tl = 0; tl < t_count; ++tl) {
        double xv = xbuf[(size_t)tl * BO + i] + biasd;
        mem = (sp ? 0.0 : mem) + xv;
        sp = (mem > 1.0);
        cnt += sp ? 1 : 0;
    }
    if (t_begin + t_count >= T_ALL) outp[i] = (float)cnt * 0.03125f;
    else { mem_st[i] = mem; cnt_st[i] = cnt | (sp ? (1 << 16) : 0); }
}

// emergency: no workspace (proven round 2)
__global__ __launch_bounds__(256) void if_fused_naive(
    const float* __restrict__ inp, const float* __restrict__ Wm,
    const float* __restrict__ bias, const float* __restrict__ mem0,
    float* __restrict__ outp)
{
    __shared__ float xr[K_DIM];
    const int i = blockIdx.x * 256 + threadIdx.x;
    const int b = i >> 11, o = i & (O_DIM - 1);
    double mem = (double)mem0[i];
    const double biasd = (double)bias[o];
    int cnt = 0; bool sp = false;
    const float* wrow = Wm + (size_t)o * K_DIM;
    for (int t = 0; t < T_ALL; ++t) {
        for (int k = threadIdx.x; k < K_DIM; k += 256)
            xr[k] = inp[((size_t)t * B_DIM + b) * K_DIM + k];
        __syncthreads();
        double d0 = 0.0, d1 = 0.0;
        for (int k = 0; k < K_DIM; k += 2) {
            d0 = fma((double)xr[k],     (double)wrow[k],     d0);
            d1 = fma((double)xr[k + 1], (double)wrow[k + 1], d1);
        }
        mem = (sp ? 0.0 : mem) + ((d0 + d1) + biasd);
        sp = (mem > 1.0);
        cnt += sp ? 1 : 0;
        __syncthreads();
    }
    outp[i] = (float)cnt * 0.03125f;
}

extern "C" void kernel_launch(void* const* d_in, const int* in_sizes, int n_in,
                              void* d_out, int out_size, void* d_ws, size_t ws_size,
                              hipStream_t stream) {
    const float* inp  = (const float*)d_in[0];   // [32,128,2048]
    const float* Wm   = (const float*)d_in[1];   // [2048,2048]
    const float* bias = (const float*)d_in[2];   // [2048]
    const float* mem0 = (const float*)d_in[3];   // [128,2048]
    float* outp = (float*)d_out;                 // [128,2048]

    const size_t st_bytes = (size_t)BO * 8 + (size_t)BO * 4;   // mem_st + cnt_st = 3 MB

    if (ws_size < st_bytes + (size_t)BO * 8) {
        if_fused_naive<<<BO / 256, 256, 0, stream>>>(inp, Wm, bias, mem0, outp);
        return;
    }

    int tc = T_ALL;   // t-planes per chunk (each t = one 128-row m-band)
    while (tc > 1 && st_bytes + (size_t)tc * BO * 8 > ws_size) tc >>= 1;

    double* mem_st = (double*)d_ws;
    int*    cnt_st = (int*)((char*)d_ws + (size_t)BO * 8);
    double* xbuf   = (double*)((char*)d_ws + st_bytes);

    for (int tb = 0; tb < T_ALL; tb += tc) {
        gemm_f64_mfma<<<dim3(O_DIM / 128, tc), 512, 0, stream>>>(inp, Wm, xbuf, tb * B_DIM);
        if_scan<<<BO / 256, 256, 0, stream>>>(xbuf, bias, mem0, mem_st, cnt_st,
                                              outp, tb, tc);
    }
}